// Round 1
// baseline (1651.537 us; speedup 1.0000x reference)
//
#include <hip/hip_runtime.h>

#define Bq 8192
#define Dq 1024
#define Hq 1024
#define CHUNK 64

static constexpr float NLOG2E = -1.4426950408889634f;

// sigmoid(a) where a_s = -log2(e)*a  ->  1/(1+2^{a_s})
__device__ __forceinline__ float sigmoid_s(float a_s) {
  return __builtin_amdgcn_rcpf(1.0f + __builtin_amdgcn_exp2f(a_s));
}

// Wt[d][h] = W[h][d] * (-log2e)   (W is (H,D) row-major)
__global__ __launch_bounds__(256) void transposeW(const float* __restrict__ W,
                                                  float* __restrict__ Wt) {
  __shared__ float tile[32][33];
  const int tx = threadIdx.x;  // 0..31
  const int ty = threadIdx.y;  // 0..7
  const int bx = blockIdx.x;   // d tile
  const int by = blockIdx.y;   // h tile
#pragma unroll
  for (int i = 0; i < 4; ++i) {
    const int h = by * 32 + ty + i * 8;
    const int d = bx * 32 + tx;
    tile[ty + i * 8][tx] = W[(size_t)h * Dq + d];
  }
  __syncthreads();
#pragma unroll
  for (int i = 0; i < 4; ++i) {
    const int d = bx * 32 + ty + i * 8;
    const int h = by * 32 + tx;
    Wt[(size_t)d * Hq + h] = tile[tx][ty + i * 8] * NLOG2E;
  }
}

// One block = 16 batch rows (4 waves x 4 batches). Lane owns h = 4*lane + 256*j + jj.
__global__ __launch_bounds__(256, 2) void nade_fwd(
    const float* __restrict__ x, const float* __restrict__ V,
    const float* __restrict__ bvec, const float* __restrict__ Wt,
    const float* __restrict__ cvec, float* __restrict__ out) {
  __shared__ float VW[2][2 * Hq];     // [buf][ V row | Wt row ]
  __shared__ float xs[16][CHUNK];
  __shared__ float bs[CHUNK];

  const int tid = threadIdx.x;
  const int wave = tid >> 6;
  const int lane = tid & 63;

  // ---- init state from c (pre-scaled by -log2e) ----
  float a[4][16], hc[4][16];
#pragma unroll
  for (int j = 0; j < 4; ++j) {
    const float4 cv = *reinterpret_cast<const float4*>(&cvec[4 * lane + 256 * j]);
    const float t0 = cv.x * NLOG2E, t1 = cv.y * NLOG2E;
    const float t2 = cv.z * NLOG2E, t3 = cv.w * NLOG2E;
    const float h0 = sigmoid_s(t0), h1 = sigmoid_s(t1);
    const float h2 = sigmoid_s(t2), h3 = sigmoid_s(t3);
#pragma unroll
    for (int k = 0; k < 4; ++k) {
      a[k][4 * j + 0] = t0; a[k][4 * j + 1] = t1;
      a[k][4 * j + 2] = t2; a[k][4 * j + 3] = t3;
      hc[k][4 * j + 0] = h0; hc[k][4 * j + 1] = h1;
      hc[k][4 * j + 2] = h2; hc[k][4 * j + 3] = h3;
    }
  }

  // ---- prologue: stage row 0 into VW[0] ----
  {
    const float4 v0 = *reinterpret_cast<const float4*>(&V[tid * 4]);
    const float4 w0 = *reinterpret_cast<const float4*>(&Wt[tid * 4]);
    *reinterpret_cast<float4*>(&VW[0][tid * 4]) = v0;
    *reinterpret_cast<float4*>(&VW[0][Hq + tid * 4]) = w0;
  }

  float pout0 = 0.f, pout1 = 0.f, pout2 = 0.f, pout3 = 0.f;
  int buf = 0;
  const int xrow = tid >> 4, xcol = (tid & 15) * 4;
  const size_t xbase = (size_t)(blockIdx.x * 16 + xrow) * Dq;

  for (int d0 = 0; d0 < Dq; d0 += CHUNK) {
    // stage x chunk (16 rows x 64 cols) and b chunk
    {
      const float4 xv = *reinterpret_cast<const float4*>(&x[xbase + d0 + xcol]);
      *reinterpret_cast<float4*>(&xs[xrow][xcol]) = xv;
      if (tid < CHUNK / 4) {
        const float4 bv = *reinterpret_cast<const float4*>(&bvec[d0 + tid * 4]);
        *reinterpret_cast<float4*>(&bs[tid * 4]) = bv;
      }
    }
    __syncthreads();  // covers xs/bs writes (and VW[0] prologue on first chunk)

#pragma unroll 4
    for (int dd = 0; dd < CHUNK; ++dd) {
      const int d = d0 + dd;
      const int dn = (d + 1 < Dq) ? d + 1 : d;
      // reg-staged prefetch of next V/Wt row (latency hides under compute)
      const float4 pv = *reinterpret_cast<const float4*>(&V[(size_t)dn * Hq + tid * 4]);
      const float4 pw = *reinterpret_cast<const float4*>(&Wt[(size_t)dn * Hq + tid * 4]);

      // LDS fragments: lane-stride 16B -> conflict-free ds_read_b128
      float vf[16], wf[16];
#pragma unroll
      for (int j = 0; j < 4; ++j) {
        *reinterpret_cast<float4*>(&vf[4 * j]) =
            *reinterpret_cast<const float4*>(&VW[buf][4 * lane + 256 * j]);
        *reinterpret_cast<float4*>(&wf[4 * j]) =
            *reinterpret_cast<const float4*>(&VW[buf][Hq + 4 * lane + 256 * j]);
      }

      // dot products (old h)
      float dot0 = 0.f, dot1 = 0.f, dot2 = 0.f, dot3 = 0.f;
#pragma unroll
      for (int j = 0; j < 16; ++j) {
        dot0 = fmaf(hc[0][j], vf[j], dot0);
        dot1 = fmaf(hc[1][j], vf[j], dot1);
        dot2 = fmaf(hc[2][j], vf[j], dot2);
        dot3 = fmaf(hc[3][j], vf[j], dot3);
      }
      // quad reduce per batch
      dot0 += __shfl_xor(dot0, 1); dot0 += __shfl_xor(dot0, 2);
      dot1 += __shfl_xor(dot1, 1); dot1 += __shfl_xor(dot1, 2);
      dot2 += __shfl_xor(dot2, 1); dot2 += __shfl_xor(dot2, 2);
      dot3 += __shfl_xor(dot3, 1); dot3 += __shfl_xor(dot3, 2);
      // select own batch (lane&3) then shared butterfly over quads
      const int t = lane & 3;
      float s = dot0;
      s = (t == 1) ? dot1 : s;
      s = (t == 2) ? dot2 : s;
      s = (t == 3) ? dot3 : s;
      s += __shfl_xor(s, 4);
      s += __shfl_xor(s, 8);
      s += __shfl_xor(s, 16);
      s += __shfl_xor(s, 32);

      // p for batch (lane&3) — one wave-wide sigmoid covers all 4 batches
      const float p = sigmoid_s((bs[dd] + s) * NLOG2E);
      if ((dd & 3) == 0) pout0 = p;
      else if ((dd & 3) == 1) pout1 = p;
      else if ((dd & 3) == 2) pout2 = p;
      else pout3 = p;

      // state update: only when x[b,d]==1 (wave-uniform scalar branch)
#pragma unroll
      for (int k = 0; k < 4; ++k) {
        const float xk = xs[wave * 4 + k][dd];
        if (__builtin_amdgcn_readfirstlane(__float_as_uint(xk)) != 0u) {
#pragma unroll
          for (int j = 0; j < 16; ++j) {
            a[k][j] += wf[j];
            hc[k][j] = sigmoid_s(a[k][j]);
          }
        }
      }

      // commit prefetched row into the other buffer, flip, sync
      *reinterpret_cast<float4*>(&VW[buf ^ 1][tid * 4]) = pv;
      *reinterpret_cast<float4*>(&VW[buf ^ 1][Hq + tid * 4]) = pw;
      buf ^= 1;
      __syncthreads();

      // coalesced output: 4 consecutive d per batch as one float4
      if ((dd & 3) == 3 && lane < 4) {
        const int b = blockIdx.x * 16 + wave * 4 + lane;
        *reinterpret_cast<float4*>(&out[(size_t)b * Dq + (d - 3)]) =
            make_float4(pout0, pout1, pout2, pout3);
      }
    }
  }
}

extern "C" void kernel_launch(void* const* d_in, const int* in_sizes, int n_in,
                              void* d_out, int out_size, void* d_ws, size_t ws_size,
                              hipStream_t stream) {
  (void)in_sizes; (void)n_in; (void)out_size; (void)ws_size;
  const float* x = (const float*)d_in[0];   // (B,D)
  const float* V = (const float*)d_in[1];   // (D,H)
  const float* b = (const float*)d_in[2];   // (D)
  const float* W = (const float*)d_in[3];   // (H,D)
  const float* c = (const float*)d_in[4];   // (H)
  float* out = (float*)d_out;               // (B,D)
  float* Wt = (float*)d_ws;                 // (D,H) pre-scaled, 4 MiB

  transposeW<<<dim3(Dq / 32, Hq / 32), dim3(32, 8), 0, stream>>>(W, Wt);
  nade_fwd<<<Bq / 16, 256, 0, stream>>>(x, V, b, Wt, c, out);
}

// Round 5
// 1393.708 us; speedup vs baseline: 1.1850x; 1.1850x over previous
//
#include <hip/hip_runtime.h>
#include <stdint.h>

#define Bq 8192
#define Dq 1024
#define Hq 1024
#define GROUP 4          // V/W rows staged per barrier
#define NGROUP (Dq / GROUP)

typedef __fp16 half2_t __attribute__((ext_vector_type(2)));

static constexpr float NLOG2E = -1.4426950408889634f;

// sigmoid(a) with t = -log2(e)*a  ->  1/(1+2^t)
__device__ __forceinline__ float sigmoid_s(float t) {
  return __builtin_amdgcn_rcpf(1.0f + __builtin_amdgcn_exp2f(t));
}

// async global->LDS, 16B per lane; lds dst is wave-uniform base (+ lane*16 by HW)
__device__ __forceinline__ void gl_lds16(const void* g, void* l) {
  __builtin_amdgcn_global_load_lds(
      (const __attribute__((address_space(1))) uint32_t*)g,
      (__attribute__((address_space(3))) uint32_t*)l, 16, 0, 0);
}

// Wt[d][h] = W[h][d] * (-log2e)
__global__ __launch_bounds__(256) void transposeW(const float* __restrict__ W,
                                                  float* __restrict__ Wt) {
  __shared__ float tile[32][33];
  const int tx = threadIdx.x, ty = threadIdx.y;
  const int bx = blockIdx.x, by = blockIdx.y;
#pragma unroll
  for (int i = 0; i < 4; ++i)
    tile[ty + i * 8][tx] = W[(size_t)(by * 32 + ty + i * 8) * Dq + bx * 32 + tx];
  __syncthreads();
#pragma unroll
  for (int i = 0; i < 4; ++i)
    Wt[(size_t)(bx * 32 + ty + i * 8) * Hq + by * 32 + tx] =
        tile[tx][ty + i * 8] * NLOG2E;
}

// Vh = (fp16)V, elementwise
__global__ __launch_bounds__(256) void convV(const float* __restrict__ V,
                                             uint32_t* __restrict__ Vh) {
  const int i = blockIdx.x * 256 + threadIdx.x;
  const float4 v = reinterpret_cast<const float4*>(V)[i];
  half2_t h0 = __builtin_amdgcn_cvt_pkrtz(v.x, v.y);
  half2_t h1 = __builtin_amdgcn_cvt_pkrtz(v.z, v.w);
  uint2 pk;
  pk.x = __builtin_bit_cast(uint32_t, h0);
  pk.y = __builtin_bit_cast(uint32_t, h1);
  reinterpret_cast<uint2*>(Vh)[i] = pk;
}

// One block = 16 batch rows (4 waves x 4 batches). Lane owns h = 4*lane+256*j+i.
__global__ __launch_bounds__(256, 2) void nade_fwd(
    const float* __restrict__ x, const uint32_t* __restrict__ Vh,
    const float* __restrict__ bvec, const float* __restrict__ Wt,
    const float* __restrict__ cvec, float* __restrict__ out) {
  __shared__ __align__(16) uint32_t Vs[2][GROUP][Hq / 2];  // fp16 pairs, 16 KB
  __shared__ __align__(16) float    Ws[2][GROUP][Hq];      // 32 KB

  const int tid = threadIdx.x;
  const int wave = tid >> 6;
  const int lane = tid & 63;
  const int b0 = blockIdx.x * 16 + wave * 4;

  // ---- state: a (f32, scaled by -log2e), h packed fp16 ----
  float a[4][16];
  half2_t hch[4][8];
#pragma unroll
  for (int j = 0; j < 4; ++j) {
    const float4 cv = *reinterpret_cast<const float4*>(&cvec[4 * lane + 256 * j]);
    const float t0 = cv.x * NLOG2E, t1 = cv.y * NLOG2E;
    const float t2 = cv.z * NLOG2E, t3 = cv.w * NLOG2E;
    const half2_t hp0 = __builtin_amdgcn_cvt_pkrtz(sigmoid_s(t0), sigmoid_s(t1));
    const half2_t hp1 = __builtin_amdgcn_cvt_pkrtz(sigmoid_s(t2), sigmoid_s(t3));
#pragma unroll
    for (int k = 0; k < 4; ++k) {
      a[k][4 * j + 0] = t0; a[k][4 * j + 1] = t1;
      a[k][4 * j + 2] = t2; a[k][4 * j + 3] = t3;
      hch[k][2 * j] = hp0; hch[k][2 * j + 1] = hp1;
    }
  }

  // ---- staging: copy rows [d0, d0+4) of Vh (8KB) and Wt (16KB) ----
  auto stage = [&](int d0, int buf) {
    const char* vsrc = (const char*)Vh + (size_t)d0 * Hq * 2;
    char* vdst = (char*)(&Vs[buf][0][0]);
#pragma unroll
    for (int q = 0; q < 2; ++q)
      gl_lds16(vsrc + q * 4096 + wave * 1024 + lane * 16,
               vdst + q * 4096 + wave * 1024);
    const char* wsrc = (const char*)(Wt + (size_t)d0 * Hq);
    char* wdst = (char*)(&Ws[buf][0][0]);
#pragma unroll
    for (int q = 0; q < 4; ++q)
      gl_lds16(wsrc + q * 4096 + wave * 1024 + lane * 16,
               wdst + q * 4096 + wave * 1024);
  };

  stage(0, 0);

  unsigned long long xm[4];
  float breg = 0.f;
  float po[4];

  __syncthreads();  // group 0 staged

  for (int g = 0; g < NGROUP; ++g) {
    const int d0 = g * GROUP;
    const int cur = g & 1;

    // per-64-step chunk: x bitmask via ballot (scalar), b row to lanes
    if ((d0 & 63) == 0) {
#pragma unroll
      for (int k = 0; k < 4; ++k) {
        const float xv = x[(size_t)(b0 + k) * Dq + d0 + lane];
        xm[k] = __ballot(xv != 0.0f);
      }
      breg = bvec[d0 + lane];
    }

    // prefetch next group's rows (async DMA into the other buffer)
    if (g + 1 < NGROUP) stage(d0 + GROUP, cur ^ 1);

#pragma unroll
    for (int ss = 0; ss < GROUP; ++ss) {
      const int d = d0 + ss;
      const int dl = d & 63;

      // fragments: lane-contiguous reads, conflict-free
      half2_t vh[8];
#pragma unroll
      for (int j = 0; j < 4; ++j) {
        const uint2 raw = *reinterpret_cast<const uint2*>(&Vs[cur][ss][2 * lane + 128 * j]);
        vh[2 * j]     = __builtin_bit_cast(half2_t, raw.x);
        vh[2 * j + 1] = __builtin_bit_cast(half2_t, raw.y);
      }
      float4 wv[4];
#pragma unroll
      for (int j = 0; j < 4; ++j)
        wv[j] = *reinterpret_cast<const float4*>(&Ws[cur][ss][4 * lane + 256 * j]);

      // dots via v_dot2_f32_f16
      float dot0 = 0.f, dot1 = 0.f, dot2 = 0.f, dot3 = 0.f;
#pragma unroll
      for (int p = 0; p < 8; ++p) {
        dot0 = __builtin_amdgcn_fdot2(hch[0][p], vh[p], dot0, false);
        dot1 = __builtin_amdgcn_fdot2(hch[1][p], vh[p], dot1, false);
        dot2 = __builtin_amdgcn_fdot2(hch[2][p], vh[p], dot2, false);
        dot3 = __builtin_amdgcn_fdot2(hch[3][p], vh[p], dot3, false);
      }
      // quad reduce per batch, select own batch, butterfly over quads
      dot0 += __shfl_xor(dot0, 1); dot0 += __shfl_xor(dot0, 2);
      dot1 += __shfl_xor(dot1, 1); dot1 += __shfl_xor(dot1, 2);
      dot2 += __shfl_xor(dot2, 1); dot2 += __shfl_xor(dot2, 2);
      dot3 += __shfl_xor(dot3, 1); dot3 += __shfl_xor(dot3, 2);
      const int t = lane & 3;
      float s = dot0;
      s = (t == 1) ? dot1 : s;
      s = (t == 2) ? dot2 : s;
      s = (t == 3) ? dot3 : s;
      s += __shfl_xor(s, 4);
      s += __shfl_xor(s, 8);
      s += __shfl_xor(s, 16);
      s += __shfl_xor(s, 32);

      const float bd = __shfl(breg, dl);
      po[ss] = sigmoid_s((bd + s) * NLOG2E);

      // state update only when x[b,d]==1 (scalar branch from ballot mask)
#pragma unroll
      for (int k = 0; k < 4; ++k) {
        if (__builtin_amdgcn_readfirstlane((uint32_t)(xm[k] >> dl)) & 1u) {
#pragma unroll
          for (int j = 0; j < 4; ++j) {
            a[k][4 * j + 0] += wv[j].x;
            a[k][4 * j + 1] += wv[j].y;
            a[k][4 * j + 2] += wv[j].z;
            a[k][4 * j + 3] += wv[j].w;
          }
#pragma unroll
          for (int p = 0; p < 8; ++p)
            hch[k][p] = __builtin_amdgcn_cvt_pkrtz(sigmoid_s(a[k][2 * p]),
                                                   sigmoid_s(a[k][2 * p + 1]));
        }
      }
    }

    // coalesced output: 4 consecutive d per batch
    if (lane < 4) {
      *reinterpret_cast<float4*>(&out[(size_t)(b0 + lane) * Dq + d0]) =
          make_float4(po[0], po[1], po[2], po[3]);
    }

    __syncthreads();  // drains vmcnt: next buffer staged; readers done with cur
  }
}

extern "C" void kernel_launch(void* const* d_in, const int* in_sizes, int n_in,
                              void* d_out, int out_size, void* d_ws, size_t ws_size,
                              hipStream_t stream) {
  (void)in_sizes; (void)n_in; (void)out_size; (void)ws_size;
  const float* x = (const float*)d_in[0];   // (B,D)
  const float* V = (const float*)d_in[1];   // (D,H)
  const float* b = (const float*)d_in[2];   // (D)
  const float* W = (const float*)d_in[3];   // (H,D)
  const float* c = (const float*)d_in[4];   // (H)
  float* out = (float*)d_out;               // (B,D)
  float* Wt = (float*)d_ws;                        // 4 MB f32, scaled
  uint32_t* Vh = (uint32_t*)((char*)d_ws + (size_t)Dq * Hq * 4);  // 2 MB fp16

  transposeW<<<dim3(Dq / 32, Hq / 32), dim3(32, 8), 0, stream>>>(W, Wt);
  convV<<<(Dq * Hq / 4) / 256, 256, 0, stream>>>(V, Vh);
  nade_fwd<<<Bq / 16, 256, 0, stream>>>(x, Vh, b, Wt, c, out);
}

// Round 7
// 1220.202 us; speedup vs baseline: 1.3535x; 1.1422x over previous
//
#include <hip/hip_runtime.h>
#include <stdint.h>

#define Bq 8192
#define Dq 1024
#define Hq 1024
#define GROUP 2
#define NGROUP (Dq / GROUP)

typedef __fp16 half2_t __attribute__((ext_vector_type(2)));

static constexpr float NLOG2E = -1.4426950408889634f;

// async global->LDS, 16B/lane; lds dst is wave-uniform base (+ lane*16 by HW)
__device__ __forceinline__ void gl_lds16(const void* g, void* l) {
  __builtin_amdgcn_global_load_lds(
      (const __attribute__((address_space(1))) uint32_t*)g,
      (__attribute__((address_space(3))) uint32_t*)l, 16, 0, 0);
}

// Et[d][h] = exp2(W[h][d] * -log2e) = e^{-w}   (W is (H,D) row-major)
__global__ __launch_bounds__(256) void prepE(const float* __restrict__ W,
                                             float* __restrict__ Et) {
  __shared__ float tile[32][33];
  const int tx = threadIdx.x, ty = threadIdx.y;
  const int bx = blockIdx.x, by = blockIdx.y;
#pragma unroll
  for (int i = 0; i < 4; ++i)
    tile[ty + i * 8][tx] = W[(size_t)(by * 32 + ty + i * 8) * Dq + bx * 32 + tx];
  __syncthreads();
#pragma unroll
  for (int i = 0; i < 4; ++i)
    Et[(size_t)(bx * 32 + ty + i * 8) * Hq + by * 32 + tx] =
        exp2f(tile[tx][ty + i * 8] * NLOG2E);
}

// Vh = fp16(V * -log2e): dot then directly yields scaled pre-activation
__global__ __launch_bounds__(256) void convV(const float* __restrict__ V,
                                             uint32_t* __restrict__ Vh) {
  const int i = blockIdx.x * 256 + threadIdx.x;
  const float4 v = reinterpret_cast<const float4*>(V)[i];
  half2_t h0 = __builtin_amdgcn_cvt_pkrtz(v.x * NLOG2E, v.y * NLOG2E);
  half2_t h1 = __builtin_amdgcn_cvt_pkrtz(v.z * NLOG2E, v.w * NLOG2E);
  uint2 pk;
  pk.x = __builtin_bit_cast(uint32_t, h0);
  pk.y = __builtin_bit_cast(uint32_t, h1);
  reinterpret_cast<uint2*>(Vh)[i] = pk;
}

// Block = 8 batch rows (4 waves x 2). Lane owns h = 4*lane + 256*j + i.
// State: r = e^{-a} (f32), h = rcp(1+r) cached packed fp16.
__global__ __launch_bounds__(256, 4) void nade_fwd(
    const float* __restrict__ x, const uint32_t* __restrict__ Vh,
    const float* __restrict__ bvec, const float* __restrict__ Et,
    const float* __restrict__ cvec, float* __restrict__ out) {
  __shared__ __align__(16) uint32_t Vs[2][GROUP][Hq / 2];  // 8 KB
  __shared__ __align__(16) float    Es[2][GROUP][Hq];      // 16 KB

  const int tid = threadIdx.x;
  const int wave = tid >> 6;
  const int lane = tid & 63;
  const int b0 = blockIdx.x * 8 + wave * 2;

  // ---- init: r = 2^{c * -log2e}, h = rcp(1+r) ----
  float r[2][16];
  half2_t hch[2][8];
#pragma unroll
  for (int j = 0; j < 4; ++j) {
    const float4 cv = *reinterpret_cast<const float4*>(&cvec[4 * lane + 256 * j]);
    const float r0 = __builtin_amdgcn_exp2f(cv.x * NLOG2E);
    const float r1 = __builtin_amdgcn_exp2f(cv.y * NLOG2E);
    const float r2 = __builtin_amdgcn_exp2f(cv.z * NLOG2E);
    const float r3 = __builtin_amdgcn_exp2f(cv.w * NLOG2E);
    const float h0 = __builtin_amdgcn_rcpf(1.0f + r0);
    const float h1 = __builtin_amdgcn_rcpf(1.0f + r1);
    const float h2 = __builtin_amdgcn_rcpf(1.0f + r2);
    const float h3 = __builtin_amdgcn_rcpf(1.0f + r3);
    const half2_t hp0 = __builtin_amdgcn_cvt_pkrtz(h0, h1);
    const half2_t hp1 = __builtin_amdgcn_cvt_pkrtz(h2, h3);
#pragma unroll
    for (int k = 0; k < 2; ++k) {
      r[k][4 * j + 0] = r0; r[k][4 * j + 1] = r1;
      r[k][4 * j + 2] = r2; r[k][4 * j + 3] = r3;
      hch[k][2 * j] = hp0; hch[k][2 * j + 1] = hp1;
    }
  }

  // ---- staging: rows [d0, d0+2) of Vh (4KB) + Et (8KB) ----
  auto stage = [&](int d0, int buf) {
    const char* vsrc = (const char*)Vh + (size_t)d0 * (Hq * 2);
    gl_lds16(vsrc + wave * 1024 + lane * 16, (char*)&Vs[buf][0][0] + wave * 1024);
    const char* esrc = (const char*)Et + (size_t)d0 * (Hq * 4);
#pragma unroll
    for (int q = 0; q < 2; ++q)
      gl_lds16(esrc + q * 4096 + wave * 1024 + lane * 16,
               (char*)&Es[buf][0][0] + q * 4096 + wave * 1024);
  };

  stage(0, 0);

  unsigned long long xm[2];
  float breg = 0.f;
  float po[4];

  __syncthreads();  // group 0 staged

  for (int g = 0; g < NGROUP; ++g) {
    const int cur = g & 1;

    // every 64 d-steps: x bitmasks via ballot (wave-uniform), b row (pre-scaled)
    if ((g & 31) == 0) {
#pragma unroll
      for (int k = 0; k < 2; ++k) {
        const float xv = x[(size_t)(b0 + k) * Dq + 2 * g + lane];
        xm[k] = __ballot(xv != 0.0f);
      }
      breg = bvec[2 * g + lane] * NLOG2E;
    }

    if (g + 1 < NGROUP) stage(2 * (g + 1), cur ^ 1);

#pragma unroll
    for (int ss = 0; ss < GROUP; ++ss) {
      const int d = 2 * g + ss;
      const int dl = d & 63;

      // V fragment: 4x ds_read_b64, lane-contiguous (conflict-free)
      half2_t vh[8];
#pragma unroll
      for (int j = 0; j < 4; ++j) {
        const uint2 raw =
            *reinterpret_cast<const uint2*>(&Vs[cur][ss][2 * lane + 128 * j]);
        vh[2 * j]     = __builtin_bit_cast(half2_t, raw.x);
        vh[2 * j + 1] = __builtin_bit_cast(half2_t, raw.y);
      }

      // dots (scaled V): 16 fdot2
      float dot0 = 0.f, dot1 = 0.f;
#pragma unroll
      for (int p = 0; p < 8; ++p) {
        dot0 = __builtin_amdgcn_fdot2(hch[0][p], vh[p], dot0, false);
        dot1 = __builtin_amdgcn_fdot2(hch[1][p], vh[p], dot1, false);
      }
      // reduce: pair-swap, select own batch (lane&1), butterfly
      dot0 += __shfl_xor(dot0, 1);
      dot1 += __shfl_xor(dot1, 1);
      float s = (lane & 1) ? dot1 : dot0;
      s += __shfl_xor(s, 2);
      s += __shfl_xor(s, 4);
      s += __shfl_xor(s, 8);
      s += __shfl_xor(s, 16);
      s += __shfl_xor(s, 32);

      const float bd = __shfl(breg, dl);
      po[2 * (g & 1) + ss] =
          __builtin_amdgcn_rcpf(1.0f + __builtin_amdgcn_exp2f(bd + s));

      // state update: r *= E only where x[b,d]==1 (wave-uniform branches)
      const uint32_t m0 = __builtin_amdgcn_readfirstlane((uint32_t)(xm[0] >> dl)) & 1u;
      const uint32_t m1 = __builtin_amdgcn_readfirstlane((uint32_t)(xm[1] >> dl)) & 1u;
      if (m0 | m1) {
        float Ef[16];
#pragma unroll
        for (int j = 0; j < 4; ++j)
          *reinterpret_cast<float4*>(&Ef[4 * j]) =
              *reinterpret_cast<const float4*>(&Es[cur][ss][4 * lane + 256 * j]);
#pragma unroll
        for (int k = 0; k < 2; ++k) {
          const uint32_t mk = k ? m1 : m0;
          if (mk) {
#pragma unroll
            for (int j = 0; j < 8; ++j) {
              const float ra = (r[k][2 * j]     *= Ef[2 * j]);
              const float rb = (r[k][2 * j + 1] *= Ef[2 * j + 1]);
              hch[k][j] = __builtin_amdgcn_cvt_pkrtz(
                  __builtin_amdgcn_rcpf(1.0f + ra),
                  __builtin_amdgcn_rcpf(1.0f + rb));
            }
          }
        }
      }
    }

    __syncthreads();  // next buffer staged; all readers done with cur

    // coalesced output: 4 consecutive d per batch, every 2 groups
    if ((g & 1) && lane < 2) {
      *reinterpret_cast<float4*>(&out[(size_t)(b0 + lane) * Dq + 2 * (g - 1)]) =
          make_float4(po[0], po[1], po[2], po[3]);
    }
  }
}

extern "C" void kernel_launch(void* const* d_in, const int* in_sizes, int n_in,
                              void* d_out, int out_size, void* d_ws, size_t ws_size,
                              hipStream_t stream) {
  (void)in_sizes; (void)n_in; (void)out_size; (void)ws_size;
  const float* x = (const float*)d_in[0];   // (B,D)
  const float* V = (const float*)d_in[1];   // (D,H)
  const float* b = (const float*)d_in[2];   // (D)
  const float* W = (const float*)d_in[3];   // (H,D)
  const float* c = (const float*)d_in[4];   // (H)
  float* out = (float*)d_out;               // (B,D)
  float* Et = (float*)d_ws;                               // 4 MB f32: e^{-w}
  uint32_t* Vh = (uint32_t*)((char*)d_ws + (size_t)Dq * Hq * 4);  // 2 MB fp16

  prepE<<<dim3(Dq / 32, Hq / 32), dim3(32, 8), 0, stream>>>(W, Et);
  convV<<<(Dq * Hq / 4) / 256, 256, 0, stream>>>(V, Vh);
  nade_fwd<<<Bq / 8, 256, 0, stream>>>(x, Vh, b, Et, c, out);
}

// Round 8
// 1130.907 us; speedup vs baseline: 1.4604x; 1.0790x over previous
//
#include <hip/hip_runtime.h>
#include <stdint.h>

#define Bq 8192
#define Dq 1024
#define Hq 1024
#define GROUP 2
#define NGROUP (Dq / GROUP)

typedef __fp16 half2_t __attribute__((ext_vector_type(2)));

static constexpr float NLOG2E = -1.4426950408889634f;

// async global->LDS, 16B/lane; lds dst is wave-uniform base (+ lane*16 by HW)
__device__ __forceinline__ void gl_lds16(const void* g, void* l) {
  __builtin_amdgcn_global_load_lds(
      (const __attribute__((address_space(1))) uint32_t*)g,
      (__attribute__((address_space(3))) uint32_t*)l, 16, 0, 0);
}

// v += v[lane perm by DPP ctrl]   (full-rate VALU, no address calc)
template <int CTRL>
__device__ __forceinline__ float dppadd(float v) {
  const int x = __builtin_bit_cast(int, v);
  const int y = __builtin_amdgcn_update_dpp(x, x, CTRL, 0xF, 0xF, false);
  return v + __builtin_bit_cast(float, y);
}

// v += v[lane ^ mask] via ds_swizzle (no address calc)
template <int OFF>
__device__ __forceinline__ float swzadd(float v) {
  const int y = __builtin_amdgcn_ds_swizzle(__builtin_bit_cast(int, v), OFF);
  return v + __builtin_bit_cast(float, y);
}

// Et[d][h] = exp2(W[h][d] * -log2e) = e^{-w}   (W is (H,D) row-major)
__global__ __launch_bounds__(256) void prepE(const float* __restrict__ W,
                                             float* __restrict__ Et) {
  __shared__ float tile[32][33];
  const int tx = threadIdx.x, ty = threadIdx.y;
  const int bx = blockIdx.x, by = blockIdx.y;
#pragma unroll
  for (int i = 0; i < 4; ++i)
    tile[ty + i * 8][tx] = W[(size_t)(by * 32 + ty + i * 8) * Dq + bx * 32 + tx];
  __syncthreads();
#pragma unroll
  for (int i = 0; i < 4; ++i)
    Et[(size_t)(bx * 32 + ty + i * 8) * Hq + by * 32 + tx] =
        exp2f(tile[tx][ty + i * 8] * NLOG2E);
}

// Vh = fp16(V * -log2e)
__global__ __launch_bounds__(256) void convV(const float* __restrict__ V,
                                             uint32_t* __restrict__ Vh) {
  const int i = blockIdx.x * 256 + threadIdx.x;
  const float4 v = reinterpret_cast<const float4*>(V)[i];
  half2_t h0 = __builtin_amdgcn_cvt_pkrtz(v.x * NLOG2E, v.y * NLOG2E);
  half2_t h1 = __builtin_amdgcn_cvt_pkrtz(v.z * NLOG2E, v.w * NLOG2E);
  uint2 pk;
  pk.x = __builtin_bit_cast(uint32_t, h0);
  pk.y = __builtin_bit_cast(uint32_t, h1);
  reinterpret_cast<uint2*>(Vh)[i] = pk;
}

// Block = 8 batch rows (4 waves x 2). Lane owns h = 4*lane + 256*j + i.
// State: r = e^{-a} (f32), h = rcp(1+r) cached packed fp16.
__global__ __launch_bounds__(256, 4) void nade_fwd(
    const float* __restrict__ x, const uint32_t* __restrict__ Vh,
    const float* __restrict__ bvec, const float* __restrict__ Et,
    const float* __restrict__ cvec, float* __restrict__ out) {
  __shared__ __align__(16) uint32_t Vs[2][GROUP][Hq / 2];  // 8 KB
  __shared__ __align__(16) float    Es[2][GROUP][Hq];      // 16 KB

  const int tid = threadIdx.x;
  const int wave = tid >> 6;
  const int lane = tid & 63;
  const bool odd = lane & 1;
  const int b0 = blockIdx.x * 8 + wave * 2;

  // ---- init: r = 2^{c * -log2e}, h = rcp(1+r) ----
  float r[2][16];
  half2_t hch[2][8];
#pragma unroll
  for (int j = 0; j < 4; ++j) {
    const float4 cv = *reinterpret_cast<const float4*>(&cvec[4 * lane + 256 * j]);
    const float r0 = __builtin_amdgcn_exp2f(cv.x * NLOG2E);
    const float r1 = __builtin_amdgcn_exp2f(cv.y * NLOG2E);
    const float r2 = __builtin_amdgcn_exp2f(cv.z * NLOG2E);
    const float r3 = __builtin_amdgcn_exp2f(cv.w * NLOG2E);
    const half2_t hp0 = __builtin_amdgcn_cvt_pkrtz(
        __builtin_amdgcn_rcpf(1.0f + r0), __builtin_amdgcn_rcpf(1.0f + r1));
    const half2_t hp1 = __builtin_amdgcn_cvt_pkrtz(
        __builtin_amdgcn_rcpf(1.0f + r2), __builtin_amdgcn_rcpf(1.0f + r3));
#pragma unroll
    for (int k = 0; k < 2; ++k) {
      r[k][4 * j + 0] = r0; r[k][4 * j + 1] = r1;
      r[k][4 * j + 2] = r2; r[k][4 * j + 3] = r3;
      hch[k][2 * j] = hp0; hch[k][2 * j + 1] = hp1;
    }
  }

  // ---- staging: rows [d0, d0+2) of Vh (4KB) + Et (8KB) into buffer buf ----
  auto stage = [&](int d0, int buf) {
    const char* vsrc = (const char*)Vh + (size_t)d0 * (Hq * 2);
    gl_lds16(vsrc + wave * 1024 + lane * 16, (char*)&Vs[buf][0][0] + wave * 1024);
    const char* esrc = (const char*)Et + (size_t)d0 * (Hq * 4);
#pragma unroll
    for (int q = 0; q < 2; ++q)
      gl_lds16(esrc + q * 4096 + wave * 1024 + lane * 16,
               (char*)&Es[buf][0][0] + q * 4096 + wave * 1024);
  };

  stage(0, 0);

  unsigned long long xm[2];  // ballot results: wave-uniform -> SGPR
  float breg = 0.f;
  float po0, po1, po2, po3;

  __syncthreads();  // group 0 staged

// one d-step: compile-time buffer CUR and slot SS
#define UPD(k)                                                              \
  {                                                                         \
    _Pragma("unroll") for (int j = 0; j < 8; ++j) {                         \
      const float ra = (r[k][2 * j] *= Ef[2 * j]);                          \
      const float rb = (r[k][2 * j + 1] *= Ef[2 * j + 1]);                  \
      hch[k][j] = __builtin_amdgcn_cvt_pkrtz(                               \
          __builtin_amdgcn_rcpf(1.0f + ra),                                 \
          __builtin_amdgcn_rcpf(1.0f + rb));                                \
    }                                                                       \
  }

#define STEP(CUR, SS, D, PO)                                                \
  {                                                                         \
    const int dl = (D)&63;                                                  \
    half2_t vh[8];                                                          \
    _Pragma("unroll") for (int j = 0; j < 4; ++j) {                         \
      const uint2 raw = *reinterpret_cast<const uint2*>(                    \
          &Vs[CUR][SS][2 * lane + 128 * j]);                                \
      vh[2 * j] = __builtin_bit_cast(half2_t, raw.x);                       \
      vh[2 * j + 1] = __builtin_bit_cast(half2_t, raw.y);                   \
    }                                                                       \
    float dot0 = 0.f, dot1 = 0.f;                                           \
    _Pragma("unroll") for (int p = 0; p < 8; ++p) {                         \
      dot0 = __builtin_amdgcn_fdot2(hch[0][p], vh[p], dot0, false);         \
      dot1 = __builtin_amdgcn_fdot2(hch[1][p], vh[p], dot1, false);         \
    }                                                                       \
    dot0 = dppadd<0xB1>(dot0); /* xor1: quad_perm(1,0,3,2) */               \
    dot1 = dppadd<0xB1>(dot1);                                              \
    float s = odd ? dot1 : dot0;                                            \
    s = dppadd<0x4E>(s);  /* xor2: quad_perm(2,3,0,1) */                    \
    s = swzadd<0x101F>(s); /* xor4 */                                       \
    s = swzadd<0x201F>(s); /* xor8 */                                       \
    s = swzadd<0x401F>(s); /* xor16 */                                      \
    s += __shfl_xor(s, 32);                                                 \
    const float bd = __shfl(breg, dl);                                      \
    PO = __builtin_amdgcn_rcpf(1.0f + __builtin_amdgcn_exp2f(bd + s));      \
    const bool a0 = (xm[0] >> dl) & 1;                                      \
    const bool a1 = (xm[1] >> dl) & 1;                                      \
    if (a0 | a1) {                                                          \
      float Ef[16];                                                         \
      _Pragma("unroll") for (int j = 0; j < 4; ++j)                         \
          *reinterpret_cast<float4*>(&Ef[4 * j]) =                          \
          *reinterpret_cast<const float4*>(&Es[CUR][SS][4 * lane + 256 * j]); \
      if (a0) UPD(0)                                                        \
      if (a1) UPD(1)                                                        \
    }                                                                       \
  }

  for (int gg = 0; gg < NGROUP; gg += 2) {
    // every 64 d-steps: x bitmasks via ballot (uniform->SGPR), pre-scaled b
    if ((gg & 31) == 0) {
#pragma unroll
      for (int k = 0; k < 2; ++k) {
        const float xv = x[(size_t)(b0 + k) * Dq + 2 * gg + lane];
        xm[k] = __ballot(xv != 0.0f);
      }
      breg = bvec[2 * gg + lane] * NLOG2E;
    }

    stage(2 * (gg + 1), 1);         // prefetch group gg+1 -> buf1
    STEP(0, 0, 2 * gg, po0)
    STEP(0, 1, 2 * gg + 1, po1)
    __syncthreads();                // buf1 staged; buf0 reads done

    if (gg + 2 < NGROUP) stage(2 * (gg + 2), 0);  // prefetch -> buf0
    STEP(1, 0, 2 * gg + 2, po2)
    STEP(1, 1, 2 * gg + 3, po3)
    __syncthreads();                // buf0 staged; buf1 reads done

    if (lane < 2) {
      *reinterpret_cast<float4*>(&out[(size_t)(b0 + lane) * Dq + 2 * gg]) =
          make_float4(po0, po1, po2, po3);
    }
  }
#undef STEP
#undef UPD
}

extern "C" void kernel_launch(void* const* d_in, const int* in_sizes, int n_in,
                              void* d_out, int out_size, void* d_ws, size_t ws_size,
                              hipStream_t stream) {
  (void)in_sizes; (void)n_in; (void)out_size; (void)ws_size;
  const float* x = (const float*)d_in[0];   // (B,D)
  const float* V = (const float*)d_in[1];   // (D,H)
  const float* b = (const float*)d_in[2];   // (D)
  const float* W = (const float*)d_in[3];   // (H,D)
  const float* c = (const float*)d_in[4];   // (H)
  float* out = (float*)d_out;               // (B,D)
  float* Et = (float*)d_ws;                               // 4 MB f32: e^{-w}
  uint32_t* Vh = (uint32_t*)((char*)d_ws + (size_t)Dq * Hq * 4);  // 2 MB fp16

  prepE<<<dim3(Dq / 32, Hq / 32), dim3(32, 8), 0, stream>>>(W, Et);
  convV<<<(Dq * Hq / 4) / 256, 256, 0, stream>>>(V, Vh);
  nade_fwd<<<Bq / 8, 256, 0, stream>>>(x, Vh, b, Et, c, out);
}

// Round 9
// 833.299 us; speedup vs baseline: 1.9819x; 1.3571x over previous
//
#include <hip/hip_runtime.h>
#include <stdint.h>

#define Bq 8192
#define Dq 1024
#define Hq 1024
#define GROUP 2
#define NGROUP (Dq / GROUP)

typedef __fp16 half2_t __attribute__((ext_vector_type(2)));

static constexpr float NLOG2E = -1.4426950408889634f;

// async global->LDS, 16B/lane; lds dst is wave-uniform base (+ lane*16 by HW)
__device__ __forceinline__ void gl_lds16(const void* g, void* l) {
  __builtin_amdgcn_global_load_lds(
      (const __attribute__((address_space(1))) uint32_t*)g,
      (__attribute__((address_space(3))) uint32_t*)l, 16, 0, 0);
}

template <int CTRL>
__device__ __forceinline__ float dppadd(float v) {
  const int x = __builtin_bit_cast(int, v);
  const int y = __builtin_amdgcn_update_dpp(x, x, CTRL, 0xF, 0xF, false);
  return v + __builtin_bit_cast(float, y);
}

template <int OFF>
__device__ __forceinline__ float swzadd(float v) {
  const int y = __builtin_amdgcn_ds_swizzle(__builtin_bit_cast(int, v), OFF);
  return v + __builtin_bit_cast(float, y);
}

// EF[d][0..1023] = fp16 E = e^{-W[h][d]}, EF[d][1024..2047] = fp16 F = 1-E
__global__ __launch_bounds__(256) void prepEF(const float* __restrict__ W,
                                              __fp16* __restrict__ EF) {
  __shared__ float tile[32][33];
  const int tx = threadIdx.x, ty = threadIdx.y;
  const int bx = blockIdx.x, by = blockIdx.y;  // bx: d tile, by: h tile
#pragma unroll
  for (int i = 0; i < 4; ++i)
    tile[ty + i * 8][tx] = W[(size_t)(by * 32 + ty + i * 8) * Dq + bx * 32 + tx];
  __syncthreads();
#pragma unroll
  for (int i = 0; i < 4; ++i) {
    const int d = bx * 32 + ty + i * 8;
    const int h = by * 32 + tx;
    const float E = exp2f(tile[tx][ty + i * 8] * NLOG2E);
    EF[(size_t)d * 2048 + h] = (__fp16)E;
    EF[(size_t)d * 2048 + 1024 + h] = (__fp16)(1.0f - E);
  }
}

// Vh = fp16(V * -log2e)
__global__ __launch_bounds__(256) void convV(const float* __restrict__ V,
                                             uint32_t* __restrict__ Vh) {
  const int i = blockIdx.x * 256 + threadIdx.x;
  const float4 v = reinterpret_cast<const float4*>(V)[i];
  half2_t h0 = __builtin_amdgcn_cvt_pkrtz(v.x * NLOG2E, v.y * NLOG2E);
  half2_t h1 = __builtin_amdgcn_cvt_pkrtz(v.z * NLOG2E, v.w * NLOG2E);
  uint2 pk;
  pk.x = __builtin_bit_cast(uint32_t, h0);
  pk.y = __builtin_bit_cast(uint32_t, h1);
  reinterpret_cast<uint2*>(Vh)[i] = pk;
}

// Block = 8 batch rows (4 waves x 2). Lane owns h = 8*lane + 512*j (j=0,1).
// State per batch: y = 1+e^{-a} (half2 x8), h = 1/y (half2 x8, Newton-tracked).
__global__ __launch_bounds__(256, 4) void nade_fwd(
    const float* __restrict__ x, const uint32_t* __restrict__ Vh,
    const float* __restrict__ bvec, const uint32_t* __restrict__ EF,
    const float* __restrict__ cvec, float* __restrict__ out) {
  __shared__ __align__(16) uint32_t Vs[2][GROUP][Hq / 2];  // fp16, 8 KB
  __shared__ __align__(16) uint32_t Es[2][GROUP][Hq];      // fp16 E|F, 16 KB

  const int tid = threadIdx.x;
  const int wave = tid >> 6;
  const int lane = tid & 63;
  const bool odd = lane & 1;
  const int b0 = blockIdx.x * 8 + wave * 2;

  // ---- init: y = 1 + 2^{c*-log2e}, h = 1/y ----
  half2_t yy[2][8], hh[2][8];
  {
    float cv[16];
#pragma unroll
    for (int q = 0; q < 2; ++q) {
      *reinterpret_cast<float4*>(&cv[8 * q]) =
          *reinterpret_cast<const float4*>(&cvec[512 * q + 8 * lane]);
      *reinterpret_cast<float4*>(&cv[8 * q + 4]) =
          *reinterpret_cast<const float4*>(&cvec[512 * q + 8 * lane + 4]);
    }
#pragma unroll
    for (int j = 0; j < 8; ++j) {
      const float y0 = 1.0f + __builtin_amdgcn_exp2f(cv[2 * j] * NLOG2E);
      const float y1 = 1.0f + __builtin_amdgcn_exp2f(cv[2 * j + 1] * NLOG2E);
      const half2_t yp = __builtin_amdgcn_cvt_pkrtz(y0, y1);
      const half2_t hp = __builtin_amdgcn_cvt_pkrtz(
          __builtin_amdgcn_rcpf(y0), __builtin_amdgcn_rcpf(y1));
#pragma unroll
      for (int k = 0; k < 2; ++k) {
        yy[k][j] = yp;
        hh[k][j] = hp;
      }
    }
  }

  // ---- staging: rows [d0, d0+2): V 4KB + EF 8KB ----
  auto stage = [&](int d0, int buf) {
    const char* vsrc = (const char*)Vh + (size_t)d0 * 2048;
    gl_lds16(vsrc + wave * 1024 + lane * 16, (char*)&Vs[buf][0][0] + wave * 1024);
    const char* esrc = (const char*)EF + (size_t)d0 * 4096;
#pragma unroll
    for (int q = 0; q < 2; ++q)
      gl_lds16(esrc + q * 4096 + wave * 1024 + lane * 16,
               (char*)&Es[buf][0][0] + q * 4096 + wave * 1024);
  };

  stage(0, 0);

  unsigned long long xm[2];
  float breg = 0.f;
  float po0, po1, po2, po3;
  const half2_t two2 = {(__fp16)2.0f, (__fp16)2.0f};

  __syncthreads();  // group 0 staged

#define UPD(k)                                                               \
  {                                                                          \
    _Pragma("unroll") for (int j = 0; j < 8; ++j) {                          \
      yy[k][j] = yy[k][j] * e[j] + f[j];       /* v_pk_fma_f16 */            \
      const half2_t t = two2 - hh[k][j] * yy[k][j]; /* pk_fma (neg) */       \
      hh[k][j] = hh[k][j] * t;                 /* v_pk_mul_f16 */            \
    }                                                                        \
  }

#define STEP(CUR, SS, D, PO)                                                 \
  {                                                                          \
    const int dl = (D)&63;                                                   \
    const char* vp = (const char*)&Vs[CUR][SS][0];                           \
    const uint4 v0 = *reinterpret_cast<const uint4*>(vp + 16 * lane);        \
    const uint4 v1 = *reinterpret_cast<const uint4*>(vp + 1024 + 16 * lane); \
    half2_t vh[8];                                                           \
    vh[0] = __builtin_bit_cast(half2_t, v0.x);                               \
    vh[1] = __builtin_bit_cast(half2_t, v0.y);                               \
    vh[2] = __builtin_bit_cast(half2_t, v0.z);                               \
    vh[3] = __builtin_bit_cast(half2_t, v0.w);                               \
    vh[4] = __builtin_bit_cast(half2_t, v1.x);                               \
    vh[5] = __builtin_bit_cast(half2_t, v1.y);                               \
    vh[6] = __builtin_bit_cast(half2_t, v1.z);                               \
    vh[7] = __builtin_bit_cast(half2_t, v1.w);                               \
    float dot0 = 0.f, dot1 = 0.f;                                            \
    _Pragma("unroll") for (int p = 0; p < 8; ++p) {                          \
      dot0 = __builtin_amdgcn_fdot2(hh[0][p], vh[p], dot0, false);           \
      dot1 = __builtin_amdgcn_fdot2(hh[1][p], vh[p], dot1, false);           \
    }                                                                        \
    dot0 = dppadd<0xB1>(dot0);                                               \
    dot1 = dppadd<0xB1>(dot1);                                               \
    float s = odd ? dot1 : dot0;                                             \
    s = dppadd<0x4E>(s);                                                     \
    s = swzadd<0x101F>(s);                                                   \
    s = swzadd<0x201F>(s);                                                   \
    s = swzadd<0x401F>(s);                                                   \
    s += __shfl_xor(s, 32);                                                  \
    const float bd = __shfl(breg, dl);                                       \
    PO = __builtin_amdgcn_rcpf(1.0f + __builtin_amdgcn_exp2f(bd + s));       \
    const bool a0 = (xm[0] >> dl) & 1;                                       \
    const bool a1 = (xm[1] >> dl) & 1;                                       \
    if (a0 | a1) {                                                           \
      const char* ep = (const char*)&Es[CUR][SS][0];                         \
      const uint4 e0 = *reinterpret_cast<const uint4*>(ep + 16 * lane);      \
      const uint4 e1 = *reinterpret_cast<const uint4*>(ep + 1024 + 16 * lane); \
      const uint4 f0 = *reinterpret_cast<const uint4*>(ep + 2048 + 16 * lane); \
      const uint4 f1 = *reinterpret_cast<const uint4*>(ep + 3072 + 16 * lane); \
      half2_t e[8], f[8];                                                    \
      e[0] = __builtin_bit_cast(half2_t, e0.x);                              \
      e[1] = __builtin_bit_cast(half2_t, e0.y);                              \
      e[2] = __builtin_bit_cast(half2_t, e0.z);                              \
      e[3] = __builtin_bit_cast(half2_t, e0.w);                              \
      e[4] = __builtin_bit_cast(half2_t, e1.x);                              \
      e[5] = __builtin_bit_cast(half2_t, e1.y);                              \
      e[6] = __builtin_bit_cast(half2_t, e1.z);                              \
      e[7] = __builtin_bit_cast(half2_t, e1.w);                              \
      f[0] = __builtin_bit_cast(half2_t, f0.x);                              \
      f[1] = __builtin_bit_cast(half2_t, f0.y);                              \
      f[2] = __builtin_bit_cast(half2_t, f0.z);                              \
      f[3] = __builtin_bit_cast(half2_t, f0.w);                              \
      f[4] = __builtin_bit_cast(half2_t, f1.x);                              \
      f[5] = __builtin_bit_cast(half2_t, f1.y);                              \
      f[6] = __builtin_bit_cast(half2_t, f1.z);                              \
      f[7] = __builtin_bit_cast(half2_t, f1.w);                              \
      if (a0) UPD(0)                                                         \
      if (a1) UPD(1)                                                         \
    }                                                                        \
  }

  for (int gg = 0; gg < NGROUP; gg += 2) {
    if ((gg & 31) == 0) {
#pragma unroll
      for (int k = 0; k < 2; ++k) {
        const float xv = x[(size_t)(b0 + k) * Dq + 2 * gg + lane];
        xm[k] = __ballot(xv != 0.0f);
      }
      breg = bvec[2 * gg + lane] * NLOG2E;
    }

    stage(2 * (gg + 1), 1);  // prefetch -> buf1
    STEP(0, 0, 2 * gg, po0)
    STEP(0, 1, 2 * gg + 1, po1)
    __syncthreads();  // buf1 staged; buf0 reads done

    if (gg + 2 < NGROUP) stage(2 * (gg + 2), 0);  // prefetch -> buf0
    STEP(1, 0, 2 * gg + 2, po2)
    STEP(1, 1, 2 * gg + 3, po3)
    __syncthreads();  // buf0 staged; buf1 reads done

    if (lane < 2) {
      *reinterpret_cast<float4*>(&out[(size_t)(b0 + lane) * Dq + 2 * gg]) =
          make_float4(po0, po1, po2, po3);
    }
  }
#undef STEP
#undef UPD
}

extern "C" void kernel_launch(void* const* d_in, const int* in_sizes, int n_in,
                              void* d_out, int out_size, void* d_ws, size_t ws_size,
                              hipStream_t stream) {
  (void)in_sizes; (void)n_in; (void)out_size; (void)ws_size;
  const float* x = (const float*)d_in[0];   // (B,D)
  const float* V = (const float*)d_in[1];   // (D,H)
  const float* b = (const float*)d_in[2];   // (D)
  const float* W = (const float*)d_in[3];   // (H,D)
  const float* c = (const float*)d_in[4];   // (H)
  float* out = (float*)d_out;               // (B,D)
  __fp16* EF = (__fp16*)d_ws;                              // 4 MB: E|F fp16 rows
  uint32_t* Vh = (uint32_t*)((char*)d_ws + (size_t)Dq * 4096);  // 2 MB fp16

  prepEF<<<dim3(Dq / 32, Hq / 32), dim3(32, 8), 0, stream>>>(W, EF);
  convV<<<(Dq * Hq / 4) / 256, 256, 0, stream>>>(V, Vh);
  nade_fwd<<<Bq / 8, 256, 0, stream>>>(x, Vh, b, (const uint32_t*)EF, c, out);
}